// Round 1
// baseline (121.932 us; speedup 1.0000x reference)
//
#include <hip/hip_runtime.h>

#define NROWS 2048
#define KDIM  768
#define L     40
#define KCH   6          // K-chunks per matrix (768 = 6 * 128)
#define KCSZ  128        // K per chunk
#define HN    (NROWS * L)   // 81920 floats per h matrix

// ---------------------------------------------------------------------------
// Kernel 1: partial projections with K split across blocks, accumulated
// directly into hx / hy via device-scope atomicAdd (k_red fused away).
//   hx[row*L+o] += sum_{k in chunk kc} x[row][k] * W1x[o][k]   (b1 NOT folded)
//   hy[row*L+o] += sum_{k in chunk kc} y[row][k] * W1y[o][k]
// grid (128 rowblocks, 6 kchunks, 2 matrices), block 256 = 16 rows x 16 segs.
// Per thread: 2 A float4 + 40*2 W float4 (W chunk 20KB -> L1 resident).
// ---------------------------------------------------------------------------
__global__ __launch_bounds__(256) void k_proj(const float* __restrict__ x,
                                              const float* __restrict__ y,
                                              const float* __restrict__ W1,
                                              float* __restrict__ hx,
                                              float* __restrict__ hy) {
    const int kc    = blockIdx.y;
    const int which = blockIdx.z;
    const float* __restrict__ A = which ? y : x;
    const int tid = threadIdx.x;
    const int r   = tid >> 4;    // 0..15 row within block
    const int seg = tid & 15;    // 0..15 K-segment (8 floats each)
    const int row0 = blockIdx.x * 16;

    // partials: [16 rows][40 o][16 segs], row stride 688 (==16 mod 32 -> 2-way = free)
    __shared__ float sh[16 * 688];

    // this thread's 8 A elements: k = kc*128 + q*64 + seg*4, q=0..1
    const float* arow = A + (size_t)(row0 + r) * KDIM + kc * KCSZ;
    float4 a0 = *(const float4*)(arow + seg * 4);
    float4 a1 = *(const float4*)(arow + 64 + seg * 4);

    const float* wbase = W1 + (size_t)which * KDIM + kc * KCSZ;
#pragma unroll 8
    for (int o = 0; o < L; ++o) {
        const float* wrow = wbase + (size_t)o * (2 * KDIM);
        float4 w0 = *(const float4*)(wrow + seg * 4);
        float4 w1 = *(const float4*)(wrow + 64 + seg * 4);
        float s = a0.x * w0.x + a0.y * w0.y + a0.z * w0.z + a0.w * w0.w
                + a1.x * w1.x + a1.y * w1.y + a1.z * w1.z + a1.w * w1.w;
        sh[r * 688 + o * 17 + seg] = s;
    }
    __syncthreads();

    // reduce 16 segments -> 640 outputs; accumulate across kc via atomics
    float* pout = (which ? hy : hx) + (size_t)row0 * L;
    for (int idx = tid; idx < 16 * L; idx += 256) {
        int rr = idx / L;
        int o  = idx - rr * L;
        float s = 0.f;
        int base = rr * 688 + o * 17;
#pragma unroll
        for (int q = 0; q < 16; ++q) s += sh[base + q];
        atomicAdd(&pout[idx], s);
    }
}

// ---------------------------------------------------------------------------
// Kernel 2: pairwise sum of exp(T_ij - 1) + diagonal T0 sum.
//   acc_ij = sum_k relu(hy[i,k] + hx[j,k] + b1[k]) * W2[k]  (b1 folded at stage)
//   sumExp += exp(acc_ij + b2 - 1);  if (i==j) sumT0 += acc_ij + b2
// Tile: BI=128 (i) x BJ=64 (j), block 256 = 16(ty,i) x 16(tx,j),
// micro-tile 8x4 with lane-interleaved rows: i = i0+ty+16u, j = j0+tx+16v.
// Last block to finish computes the final scalar (k_fin fused away).
// ---------------------------------------------------------------------------
#define BI 128
#define BJ 64
#define STRD 44

__global__ __launch_bounds__(256) void k_pair(const float* __restrict__ hx,
                                              const float* __restrict__ hy,
                                              const float* __restrict__ W2,
                                              const float* __restrict__ b1,
                                              const float* __restrict__ b2p,
                                              float* __restrict__ sums,
                                              float* __restrict__ out) {
    __shared__ float shy[BI * STRD];
    __shared__ float shx[BJ * STRD];
    __shared__ float sw2[STRD];
    __shared__ float red[8];

    const int tid = threadIdx.x;
    const int i0 = blockIdx.x * BI;
    const int j0 = blockIdx.y * BJ;

    for (int idx = tid; idx < BI * 10; idx += 256) {
        int rr = idx / 10, c = idx - rr * 10;
        float4 v = ((const float4*)(hy + (size_t)i0 * L))[idx];
        *(float4*)(shy + rr * STRD + c * 4) = v;
    }
    for (int idx = tid; idx < BJ * 10; idx += 256) {
        int rr = idx / 10, c = idx - rr * 10;
        float4 v = ((const float4*)(hx + (size_t)j0 * L))[idx];
        float4 bv = ((const float4*)b1)[c];          // fold b1 here (k_red gone)
        v.x += bv.x; v.y += bv.y; v.z += bv.z; v.w += bv.w;
        *(float4*)(shx + rr * STRD + c * 4) = v;
    }
    if (tid < 10) ((float4*)sw2)[tid] = ((const float4*)W2)[tid];
    __syncthreads();

    const int tx = tid & 15, ty = tid >> 4;

    float acc[8][4];
#pragma unroll
    for (int u = 0; u < 8; ++u)
#pragma unroll
        for (int v = 0; v < 4; ++v) acc[u][v] = 0.f;

#pragma unroll
    for (int k4 = 0; k4 < 10; ++k4) {
        float4 w = *(const float4*)(sw2 + k4 * 4);
        float4 ay[8], ax[4];
#pragma unroll
        for (int u = 0; u < 8; ++u)
            ay[u] = *(const float4*)(shy + (ty + 16 * u) * STRD + k4 * 4);
#pragma unroll
        for (int v = 0; v < 4; ++v)
            ax[v] = *(const float4*)(shx + (tx + 16 * v) * STRD + k4 * 4);
#pragma unroll
        for (int u = 0; u < 8; ++u)
#pragma unroll
            for (int v = 0; v < 4; ++v) {
                float t;
                t = ay[u].x + ax[v].x; t = fmaxf(t, 0.f); acc[u][v] += t * w.x;
                t = ay[u].y + ax[v].y; t = fmaxf(t, 0.f); acc[u][v] += t * w.y;
                t = ay[u].z + ax[v].z; t = fmaxf(t, 0.f); acc[u][v] += t * w.z;
                t = ay[u].w + ax[v].w; t = fmaxf(t, 0.f); acc[u][v] += t * w.w;
            }
    }

    const float b2v = b2p[0];
    const float c1  = b2v - 1.f;   // fold (+b2, -1) into one constant
    float sumE = 0.f, sumT = 0.f;
#pragma unroll
    for (int u = 0; u < 8; ++u)
#pragma unroll
        for (int v = 0; v < 4; ++v) {
            int gi = i0 + ty + 16 * u;
            int gj = j0 + tx + 16 * v;
            float val = acc[u][v];
            if (gi == gj) sumT += val + b2v;
            sumE += __expf(val + c1);
        }

#pragma unroll
    for (int off = 32; off > 0; off >>= 1) {
        sumE += __shfl_down(sumE, off);
        sumT += __shfl_down(sumT, off);
    }
    int wid = tid >> 6;
    if ((tid & 63) == 0) { red[wid] = sumE; red[4 + wid] = sumT; }
    __syncthreads();
    if (tid == 0) {
        float e = red[0] + red[1] + red[2] + red[3];
        float t = red[4] + red[5] + red[6] + red[7];
        atomicAdd(&sums[1], e);
        atomicAdd(&sums[0], t);
        __threadfence();
        // last block computes the final scalar (fused k_fin)
        unsigned total = gridDim.x * gridDim.y;
        unsigned prev = __hip_atomic_fetch_add((unsigned*)(sums + 2), 1u,
                                               __ATOMIC_ACQ_REL,
                                               __HIP_MEMORY_SCOPE_AGENT);
        if (prev == total - 1) {
            float st = __hip_atomic_load(sums + 0, __ATOMIC_RELAXED,
                                         __HIP_MEMORY_SCOPE_AGENT);
            float se = __hip_atomic_load(sums + 1, __ATOMIC_RELAXED,
                                         __HIP_MEMORY_SCOPE_AGENT);
            const float invN = 1.0f / (float)NROWS;
            out[0] = st * invN - se * invN * invN;
        }
    }
}

extern "C" void kernel_launch(void* const* d_in, const int* in_sizes, int n_in,
                              void* d_out, int out_size, void* d_ws, size_t ws_size,
                              hipStream_t stream) {
    const float* x  = (const float*)d_in[0];
    const float* y  = (const float*)d_in[1];
    const float* W1 = (const float*)d_in[2];
    const float* b1 = (const float*)d_in[3];
    const float* W2 = (const float*)d_in[4];
    const float* b2 = (const float*)d_in[5];
    float* out = (float*)d_out;

    float* wsf  = (float*)d_ws;
    float* sums = wsf;                   // [0]=sumT0, [1]=sumExp, [2]=block counter
    float* hx   = wsf + 16;              // 2048*40 (no b1)
    float* hy   = hx + HN;               // 2048*40

    // zero sums + counter + hx + hy in one shot (0.64 MB)
    hipMemsetAsync(wsf, 0, (16 + 2 * HN) * sizeof(float), stream);
    k_proj<<<dim3(NROWS / 16, KCH, 2), 256, 0, stream>>>(x, y, W1, hx, hy);
    k_pair<<<dim3(NROWS / BI, NROWS / BJ), 256, 0, stream>>>(hx, hy, W2, b1, b2, sums, out);
}